// Round 6
// baseline (1127.662 us; speedup 1.0000x reference)
//
#include <hip/hip_runtime.h>
#include <cstdint>
#include <cstddef>

typedef float f32x4 __attribute__((ext_vector_type(4)));
typedef float f32x16 __attribute__((ext_vector_type(16)));
typedef int i32x4 __attribute__((ext_vector_type(4)));
typedef int i32x8 __attribute__((ext_vector_type(8)));
typedef unsigned char u8;

// ---------------- async global->LDS (16B per lane, linear dest) ----------------
static __device__ __forceinline__ void gload_lds16(const void* g, void* l) {
  __builtin_amdgcn_global_load_lds(
      (__attribute__((address_space(1))) void*)(void*)g,
      (__attribute__((address_space(3))) void*)l,
      16, 0, 0);
}

// ---------------- fp8 e4m3fn (OCP) conversion, RNE ----------------
#if defined(__has_builtin)
#if __has_builtin(__builtin_amdgcn_cvt_pk_fp8_f32)
#define HAVE_HW_FP8 1
#endif
#endif

__device__ __forceinline__ u8 f32_to_e4m3_sw(float x) {
  unsigned s = (__float_as_uint(x) >> 24) & 0x80;
  float ax = fabsf(x);
  if (!(ax > 0.0f)) return (u8)s;
  if (ax >= 448.0f) return (u8)(s | 0x7e);
  if (ax < 0.015625f) {            // subnormal, step 2^-9
    int m = (int)rintf(ax * 512.0f);
    if (m >= 8) return (u8)(s | 0x08);
    return (u8)(s | m);
  }
  int e = ilogbf(ax);
  int m = (int)rintf(ldexpf(ax, 3 - e));
  if (m == 16) { ++e; m = 8; }
  return (u8)(s | ((e + 7) << 3) | (m - 8));
}

__device__ __forceinline__ unsigned cvt4_fp8(float a, float b, float c, float d) {
#ifdef HAVE_HW_FP8
  int lo = __builtin_amdgcn_cvt_pk_fp8_f32(a, b, 0, false);
  return (unsigned)__builtin_amdgcn_cvt_pk_fp8_f32(c, d, lo, true);
#else
  return (unsigned)f32_to_e4m3_sw(a) | ((unsigned)f32_to_e4m3_sw(b) << 8) |
         ((unsigned)f32_to_e4m3_sw(c) << 16) | ((unsigned)f32_to_e4m3_sw(d) << 24);
#endif
}

// ---------------- amax reduction (abs-max via unsigned-bits atomicMax) ----------------
__global__ __launch_bounds__(256) void amax_kernel(const float* __restrict__ src, size_t n4,
                                                   unsigned* __restrict__ out) {
  float m = 0.0f;
  size_t stride = (size_t)gridDim.x * blockDim.x;
  const f32x4* p = (const f32x4*)src;
  for (size_t i = (size_t)blockIdx.x * blockDim.x + threadIdx.x; i < n4; i += stride) {
    f32x4 v = p[i];
    m = fmaxf(m, fmaxf(fmaxf(fabsf(v[0]), fabsf(v[1])), fmaxf(fabsf(v[2]), fabsf(v[3]))));
  }
#pragma unroll
  for (int off = 32; off > 0; off >>= 1) m = fmaxf(m, __shfl_down(m, off));
  __shared__ float red[4];
  int lane = threadIdx.x & 63, wid = threadIdx.x >> 6;
  if (lane == 0) red[wid] = m;
  __syncthreads();
  if (threadIdx.x == 0) {
    float v = fmaxf(fmaxf(red[0], red[1]), fmaxf(red[2], red[3]));
    atomicMax(out, __float_as_uint(v));
  }
}

// ---------------- elementwise quantize (8 elems/thread) ----------------
__global__ __launch_bounds__(256) void quant_kernel(const float* __restrict__ src,
                                                    u8* __restrict__ dst,
                                                    const unsigned* __restrict__ amax_bits,
                                                    size_t n8) {
  float amax = __uint_as_float(*amax_bits);
  float scale = 448.0f / fmaxf(amax, 1e-12f);
  size_t stride = (size_t)gridDim.x * blockDim.x;
  const f32x4* p = (const f32x4*)src;
  uint2* q = (uint2*)dst;
  for (size_t i = (size_t)blockIdx.x * blockDim.x + threadIdx.x; i < n8; i += stride) {
    f32x4 a = p[2 * i], b = p[2 * i + 1];
    float a0 = fminf(fmaxf(a[0] * scale, -448.f), 448.f);
    float a1 = fminf(fmaxf(a[1] * scale, -448.f), 448.f);
    float a2 = fminf(fmaxf(a[2] * scale, -448.f), 448.f);
    float a3 = fminf(fmaxf(a[3] * scale, -448.f), 448.f);
    float b0 = fminf(fmaxf(b[0] * scale, -448.f), 448.f);
    float b1 = fminf(fmaxf(b[1] * scale, -448.f), 448.f);
    float b2 = fminf(fmaxf(b[2] * scale, -448.f), 448.f);
    float b3 = fminf(fmaxf(b[3] * scale, -448.f), 448.f);
    uint2 r;
    r.x = cvt4_fp8(a0, a1, a2, a3);
    r.y = cvt4_fp8(b0, b1, b2, b3);
    q[i] = r;
  }
}

// ---------------- transpose + quantize: src [R][C] f32 -> dst [C][R] fp8 ----------------
__global__ __launch_bounds__(256) void quantT_kernel(const float* __restrict__ src,
                                                     u8* __restrict__ dst,
                                                     const unsigned* __restrict__ amax_bits,
                                                     int R, int C) {
  __shared__ float t[64][65];
  float amax = __uint_as_float(*amax_bits);
  float scale = 448.0f / fmaxf(amax, 1e-12f);
  int nbr = R >> 6;
  int br = (int)blockIdx.x % nbr, bc = (int)blockIdx.x / nbr;
  int r0 = br * 64, c0 = bc * 64;
  int tid = threadIdx.x;
  int lc = tid & 63, lr = tid >> 6;
#pragma unroll
  for (int i = 0; i < 16; ++i)
    t[lr + i * 4][lc] = src[(size_t)(r0 + lr + i * 4) * C + c0 + lc];
  __syncthreads();
  int qd = tid & 15, xbase = tid >> 4;
#pragma unroll
  for (int i = 0; i < 4; ++i) {
    int x = xbase + 16 * i;  // output row index (column of src tile)
    float v0 = fminf(fmaxf(t[4 * qd + 0][x] * scale, -448.f), 448.f);
    float v1 = fminf(fmaxf(t[4 * qd + 1][x] * scale, -448.f), 448.f);
    float v2 = fminf(fmaxf(t[4 * qd + 2][x] * scale, -448.f), 448.f);
    float v3 = fminf(fmaxf(t[4 * qd + 3][x] * scale, -448.f), 448.f);
    *(unsigned*)(dst + (size_t)(c0 + x) * R + r0 + 4 * qd) = cvt4_fp8(v0, v1, v2, v3);
  }
}

// ---------------- LDS address swizzle ----------------
// 16B-block XOR within 64B row, key = (row>>2)&3 (period 16 rows; verified
// conflict-free in rounds 3/5: SQ_LDS_BANK_CONFLICT == 0).
__device__ __forceinline__ int swz_key(int r) { return (r >> 2) & 3; }

__device__ __forceinline__ int swz_off32(int r, int h) {
  return r * 64 + ((((h << 1) ^ swz_key(r)) << 4));
}

// Load a 32B MX-fp8 fragment (k-half h of row r) from a swizzled [*][64] tile.
__device__ __forceinline__ i32x8 ld_frag(const u8* base, int r, int h) {
  int o = swz_off32(r, h);
  i32x8 f;
  f.lo = *(const i32x4*)(base + o);
  f.hi = *(const i32x4*)(base + (o ^ 16));
  return f;
}

#define MFMA_MX(a, b, c) \
  __builtin_amdgcn_mfma_scale_f32_32x32x64_f8f6f4((a), (b), (c), 0, 0, 0, 0x7F7F7F7F, 0, 0x7F7F7F7F)

// ---------------- GEMM1: gate/up fused, NT, MX-fp8, 128x128, 4 waves ----------------
// 3-deep pipeline with COUNTED vmcnt + raw s_barrier (no __syncthreads -> no
// vmcnt(0) drain in the loop; round-5 lesson: __syncthreads lowers to a full
// vmcnt(0) lgkmcnt(0) drain, killing any prefetch).
__global__ __launch_bounds__(256, 2) void gemm1_gateup(
    const u8* __restrict__ Aq, const u8* __restrict__ Wq, const u8* __restrict__ Vq,
    const unsigned* __restrict__ scal, float* __restrict__ inter,
    unsigned* __restrict__ amax_mid, int M, int N, int K) {
  __shared__ __align__(16) u8 lA[3][8192], lW[3][8192], lV[3][8192];
  __shared__ float red[4];
  int tid = threadIdx.x;
  int lane = tid & 63, wid = tid >> 6;
  int wm = wid >> 1, wn = wid & 1;  // 2M x 2N waves, per-wave 64x64

  int nbn = N >> 7;
  int nwg = (int)gridDim.x;
  int bid = (int)blockIdx.x;
  int cpx = nwg >> 3;
  int swz = (bid & 7) * cpx + (bid >> 3);  // nwg % 8 == 0
  int bm = swz / nbn, bn = swz - bm * nbn;

  int r0 = tid >> 2;                           // 0..63
  int kblk = ((tid & 3) ^ swz_key(r0)) << 4;   // pre-swizzled global source chunk
  const u8* aS = Aq + (size_t)(bm * 128 + r0) * K + kblk;
  const u8* wS = Wq + (size_t)(bn * 128 + r0) * K + kblk;
  const u8* vS = Vq + (size_t)(bn * 128 + r0) * K + kblk;
  size_t rK = (size_t)64 * K;                  // rows 64..127 (swz_key period 16 -> same kblk)

#define STAGE1(buf, off)                                     \
  do {                                                       \
    gload_lds16(aS + (off),      lA[buf] + tid * 16);        \
    gload_lds16(aS + (off) + rK, lA[buf] + 4096 + tid * 16); \
    gload_lds16(wS + (off),      lW[buf] + tid * 16);        \
    gload_lds16(wS + (off) + rK, lW[buf] + 4096 + tid * 16); \
    gload_lds16(vS + (off),      lV[buf] + tid * 16);        \
    gload_lds16(vS + (off) + rK, lV[buf] + 4096 + tid * 16); \
  } while (0)

  f32x16 g[2][2], u[2][2];
#pragma unroll
  for (int m = 0; m < 2; ++m)
#pragma unroll
    for (int n = 0; n < 2; ++n) {
      g[m][n] = (f32x16)(0.f);
      u[m][n] = (f32x16)(0.f);
    }

  int rfrag = lane & 31;
  int h = lane >> 5;
  int arow = wm * 64 + rfrag;
  int brow = wn * 64 + rfrag;

  int NT = K >> 6;
  STAGE1(0, 0);        // 6 loads
  STAGE1(1, 64);       // 12 in flight

  for (int t = 0; t < NT; ++t) {
    unsigned cur = (unsigned)t % 3u;
    __builtin_amdgcn_s_barrier();  // buf[(t+2)%3] free (read last iter by all waves)
    if (t + 2 < NT) {
      STAGE1((cur + 2) % 3u, (t + 2) * 64);
      asm volatile("s_waitcnt vmcnt(12)" ::: "memory");  // tile t's 6 loads retired
    } else if (t + 1 < NT) {
      asm volatile("s_waitcnt vmcnt(6)" ::: "memory");
    } else {
      asm volatile("s_waitcnt vmcnt(0)" ::: "memory");
    }
    __builtin_amdgcn_s_barrier();  // buf[t%3] complete for all waves
    const u8* bA = lA[cur];
    const u8* bW = lW[cur];
    const u8* bV = lV[cur];
    i32x8 a0 = ld_frag(bA, arow, h);
    i32x8 a1 = ld_frag(bA, arow + 32, h);
    i32x8 w0 = ld_frag(bW, brow, h);
    i32x8 w1 = ld_frag(bW, brow + 32, h);
    i32x8 v0 = ld_frag(bV, brow, h);
    i32x8 v1 = ld_frag(bV, brow + 32, h);
    __builtin_amdgcn_s_setprio(1);
    g[0][0] = MFMA_MX(a0, w0, g[0][0]);
    g[0][1] = MFMA_MX(a0, w1, g[0][1]);
    g[1][0] = MFMA_MX(a1, w0, g[1][0]);
    g[1][1] = MFMA_MX(a1, w1, g[1][1]);
    u[0][0] = MFMA_MX(a0, v0, u[0][0]);
    u[0][1] = MFMA_MX(a0, v1, u[0][1]);
    u[1][0] = MFMA_MX(a1, v0, u[1][0]);
    u[1][1] = MFMA_MX(a1, v1, u[1][1]);
    __builtin_amdgcn_s_setprio(0);
  }
#undef STAGE1

  float ax = __uint_as_float(scal[0]);
  float aw = __uint_as_float(scal[1]);
  float av = __uint_as_float(scal[2]);
  float inv_x = 1.0f / (448.0f / fmaxf(ax, 1e-12f));
  float inv_w = 1.0f / (448.0f / fmaxf(aw, 1e-12f));
  float inv_v = 1.0f / (448.0f / fmaxf(av, 1e-12f));
  float sg = inv_x * inv_w, su = inv_x * inv_v;

  // C/D layout 32x32: col = lane&31, row = (reg&3) + 8*(reg>>2) + 4*(lane>>5)
  int rb = bm * 128 + wm * 64 + h * 4;
  int cb = bn * 128 + wn * 64 + rfrag;
  float lmax = 0.0f;
#pragma unroll
  for (int m = 0; m < 2; ++m)
#pragma unroll
    for (int n = 0; n < 2; ++n)
#pragma unroll
      for (int q = 0; q < 16; ++q) {
        int rr = rb + m * 32 + (q & 3) + 8 * (q >> 2);
        float gv = g[m][n][q] * sg;
        float uv = u[m][n][q] * su;
        float iv = gv / (1.0f + expf(-gv)) * uv;  // silu(g)*u
        inter[(size_t)rr * N + (cb + n * 32)] = iv;
        lmax = fmaxf(lmax, fabsf(iv));
      }
#pragma unroll
  for (int off = 32; off > 0; off >>= 1) lmax = fmaxf(lmax, __shfl_down(lmax, off));
  if (lane == 0) red[wid] = lmax;
  __syncthreads();
  if (tid == 0)
    atomicMax(amax_mid, __float_as_uint(fmaxf(fmaxf(red[0], red[1]), fmaxf(red[2], red[3]))));
}

// ---------------- GEMM2: down proj, NT vs pre-transposed w2, 128x128 ----------------
__global__ __launch_bounds__(256, 2) void gemm2_down(
    const u8* __restrict__ Aq, const u8* __restrict__ Bq,
    const unsigned* __restrict__ amax_a, const unsigned* __restrict__ amax_b,
    float* __restrict__ out, int M, int N, int K) {
  __shared__ __align__(16) u8 lA[3][8192], lB[3][8192];
  int tid = threadIdx.x;
  int lane = tid & 63, wid = tid >> 6;
  int wm = wid >> 1, wn = wid & 1;

  int nbn = N >> 7;
  int nwg = (int)gridDim.x;
  int bid = (int)blockIdx.x;
  int cpx = nwg >> 3;
  int swz = (bid & 7) * cpx + (bid >> 3);
  int bm = swz / nbn, bn = swz - bm * nbn;

  int r0 = tid >> 2;
  int kblk = ((tid & 3) ^ swz_key(r0)) << 4;
  const u8* aS = Aq + (size_t)(bm * 128 + r0) * K + kblk;
  const u8* bS = Bq + (size_t)(bn * 128 + r0) * K + kblk;
  size_t rK = (size_t)64 * K;

#define STAGE2(buf, off)                                     \
  do {                                                       \
    gload_lds16(aS + (off),      lA[buf] + tid * 16);        \
    gload_lds16(aS + (off) + rK, lA[buf] + 4096 + tid * 16); \
    gload_lds16(bS + (off),      lB[buf] + tid * 16);        \
    gload_lds16(bS + (off) + rK, lB[buf] + 4096 + tid * 16); \
  } while (0)

  f32x16 acc[2][2];
#pragma unroll
  for (int m = 0; m < 2; ++m)
#pragma unroll
    for (int n = 0; n < 2; ++n) acc[m][n] = (f32x16)(0.f);

  int rfrag = lane & 31;
  int h = lane >> 5;
  int arow = wm * 64 + rfrag;
  int brow = wn * 64 + rfrag;

  int NT = K >> 6;
  STAGE2(0, 0);
  STAGE2(1, 64);

  for (int t = 0; t < NT; ++t) {
    unsigned cur = (unsigned)t % 3u;
    __builtin_amdgcn_s_barrier();
    if (t + 2 < NT) {
      STAGE2((cur + 2) % 3u, (t + 2) * 64);
      asm volatile("s_waitcnt vmcnt(8)" ::: "memory");
    } else if (t + 1 < NT) {
      asm volatile("s_waitcnt vmcnt(4)" ::: "memory");
    } else {
      asm volatile("s_waitcnt vmcnt(0)" ::: "memory");
    }
    __builtin_amdgcn_s_barrier();
    const u8* bA = lA[cur];
    const u8* bB = lB[cur];
    i32x8 a0 = ld_frag(bA, arow, h);
    i32x8 a1 = ld_frag(bA, arow + 32, h);
    i32x8 b0 = ld_frag(bB, brow, h);
    i32x8 b1 = ld_frag(bB, brow + 32, h);
    __builtin_amdgcn_s_setprio(1);
    acc[0][0] = MFMA_MX(a0, b0, acc[0][0]);
    acc[0][1] = MFMA_MX(a0, b1, acc[0][1]);
    acc[1][0] = MFMA_MX(a1, b0, acc[1][0]);
    acc[1][1] = MFMA_MX(a1, b1, acc[1][1]);
    __builtin_amdgcn_s_setprio(0);
  }
#undef STAGE2

  float sa = 1.0f / (448.0f / fmaxf(__uint_as_float(*amax_a), 1e-12f));
  float sb = 1.0f / (448.0f / fmaxf(__uint_as_float(*amax_b), 1e-12f));
  float sc = sa * sb;

  int rb = bm * 128 + wm * 64 + h * 4;
  int cb = bn * 128 + wn * 64 + rfrag;
#pragma unroll
  for (int m = 0; m < 2; ++m)
#pragma unroll
    for (int n = 0; n < 2; ++n)
#pragma unroll
      for (int q = 0; q < 16; ++q) {
        int rr = rb + m * 32 + (q & 3) + 8 * (q >> 2);
        out[(size_t)rr * N + (cb + n * 32)] = acc[m][n][q] * sc;
      }
}

// ---------------- host launcher ----------------
extern "C" void kernel_launch(void* const* d_in, const int* in_sizes, int n_in,
                              void* d_out, int out_size, void* d_ws, size_t ws_size,
                              hipStream_t stream) {
  const float* x  = (const float*)d_in[0];
  const float* w1 = (const float*)d_in[1];
  const float* v1 = (const float*)d_in[2];
  const float* w2 = (const float*)d_in[3];
  const int M = 4096, H = 4096, F = 10752;

  u8* ws = (u8*)d_ws;
  unsigned* scal = (unsigned*)ws;          // [0]=x [1]=w1 [2]=v1 [3]=w2 [4]=mid
  u8* xq   = ws + 256;
  u8* w1q  = xq   + (size_t)M * H;
  u8* v1q  = w1q  + (size_t)F * H;
  u8* w2qT = v1q  + (size_t)F * H;
  u8* midq = w2qT + (size_t)F * H;
  float* inter = (float*)(midq + (size_t)M * F);

  hipMemsetAsync(scal, 0, 256, stream);
  amax_kernel<<<2048, 256, 0, stream>>>(x,  (size_t)M * H / 4, scal + 0);
  amax_kernel<<<2048, 256, 0, stream>>>(w1, (size_t)F * H / 4, scal + 1);
  amax_kernel<<<2048, 256, 0, stream>>>(v1, (size_t)F * H / 4, scal + 2);
  amax_kernel<<<2048, 256, 0, stream>>>(w2, (size_t)F * H / 4, scal + 3);

  quant_kernel<<<2048, 256, 0, stream>>>(x,  xq,  scal + 0, (size_t)M * H / 8);
  quant_kernel<<<2048, 256, 0, stream>>>(w1, w1q, scal + 1, (size_t)F * H / 8);
  quant_kernel<<<2048, 256, 0, stream>>>(v1, v1q, scal + 2, (size_t)F * H / 8);
  quantT_kernel<<<(F / 64) * (H / 64), 256, 0, stream>>>(w2, w2qT, scal + 3, F, H);

  gemm1_gateup<<<(M / 128) * (F / 128), 256, 0, stream>>>(xq, w1q, v1q, scal, inter,
                                                          scal + 4, M, F, H);
  quant_kernel<<<2048, 256, 0, stream>>>(inter, midq, scal + 4, (size_t)M * F / 8);
  gemm2_down<<<(M / 128) * (H / 128), 256, 0, stream>>>(midq, w2qT, scal + 4, scal + 3,
                                                        (float*)d_out, M, H, F);
}

// Round 8
// 1017.554 us; speedup vs baseline: 1.1082x; 1.1082x over previous
//
#include <hip/hip_runtime.h>
#include <cstdint>
#include <cstddef>

typedef float f32x4 __attribute__((ext_vector_type(4)));
typedef float f32x16 __attribute__((ext_vector_type(16)));
typedef int i32x4 __attribute__((ext_vector_type(4)));
typedef int i32x8 __attribute__((ext_vector_type(8)));
typedef unsigned char u8;

// ---------------- async global->LDS (16B per lane, linear dest) ----------------
static __device__ __forceinline__ void gload_lds16(const void* g, void* l) {
  __builtin_amdgcn_global_load_lds(
      (__attribute__((address_space(1))) void*)(void*)g,
      (__attribute__((address_space(3))) void*)l,
      16, 0, 0);
}

// ---------------- fp8 e4m3fn (OCP) conversion, RNE ----------------
#if defined(__has_builtin)
#if __has_builtin(__builtin_amdgcn_cvt_pk_fp8_f32)
#define HAVE_HW_FP8 1
#endif
#endif

__device__ __forceinline__ u8 f32_to_e4m3_sw(float x) {
  unsigned s = (__float_as_uint(x) >> 24) & 0x80;
  float ax = fabsf(x);
  if (!(ax > 0.0f)) return (u8)s;
  if (ax >= 448.0f) return (u8)(s | 0x7e);
  if (ax < 0.015625f) {            // subnormal, step 2^-9
    int m = (int)rintf(ax * 512.0f);
    if (m >= 8) return (u8)(s | 0x08);
    return (u8)(s | m);
  }
  int e = ilogbf(ax);
  int m = (int)rintf(ldexpf(ax, 3 - e));
  if (m == 16) { ++e; m = 8; }
  return (u8)(s | ((e + 7) << 3) | (m - 8));
}

__device__ __forceinline__ unsigned cvt4_fp8(float a, float b, float c, float d) {
#ifdef HAVE_HW_FP8
  int lo = __builtin_amdgcn_cvt_pk_fp8_f32(a, b, 0, false);
  return (unsigned)__builtin_amdgcn_cvt_pk_fp8_f32(c, d, lo, true);
#else
  return (unsigned)f32_to_e4m3_sw(a) | ((unsigned)f32_to_e4m3_sw(b) << 8) |
         ((unsigned)f32_to_e4m3_sw(c) << 16) | ((unsigned)f32_to_e4m3_sw(d) << 24);
#endif
}

// ---------------- amax reduction (abs-max via unsigned-bits atomicMax) ----------------
__global__ __launch_bounds__(256) void amax_kernel(const float* __restrict__ src, size_t n4,
                                                   unsigned* __restrict__ out) {
  float m = 0.0f;
  size_t stride = (size_t)gridDim.x * blockDim.x;
  const f32x4* p = (const f32x4*)src;
  for (size_t i = (size_t)blockIdx.x * blockDim.x + threadIdx.x; i < n4; i += stride) {
    f32x4 v = p[i];
    m = fmaxf(m, fmaxf(fmaxf(fabsf(v[0]), fabsf(v[1])), fmaxf(fabsf(v[2]), fabsf(v[3]))));
  }
#pragma unroll
  for (int off = 32; off > 0; off >>= 1) m = fmaxf(m, __shfl_down(m, off));
  __shared__ float red[4];
  int lane = threadIdx.x & 63, wid = threadIdx.x >> 6;
  if (lane == 0) red[wid] = m;
  __syncthreads();
  if (threadIdx.x == 0) {
    float v = fmaxf(fmaxf(red[0], red[1]), fmaxf(red[2], red[3]));
    atomicMax(out, __float_as_uint(v));
  }
}

// ---------------- elementwise quantize (8 elems/thread) ----------------
__global__ __launch_bounds__(256) void quant_kernel(const float* __restrict__ src,
                                                    u8* __restrict__ dst,
                                                    const unsigned* __restrict__ amax_bits,
                                                    size_t n8) {
  float amax = __uint_as_float(*amax_bits);
  float scale = 448.0f / fmaxf(amax, 1e-12f);
  size_t stride = (size_t)gridDim.x * blockDim.x;
  const f32x4* p = (const f32x4*)src;
  uint2* q = (uint2*)dst;
  for (size_t i = (size_t)blockIdx.x * blockDim.x + threadIdx.x; i < n8; i += stride) {
    f32x4 a = p[2 * i], b = p[2 * i + 1];
    float a0 = fminf(fmaxf(a[0] * scale, -448.f), 448.f);
    float a1 = fminf(fmaxf(a[1] * scale, -448.f), 448.f);
    float a2 = fminf(fmaxf(a[2] * scale, -448.f), 448.f);
    float a3 = fminf(fmaxf(a[3] * scale, -448.f), 448.f);
    float b0 = fminf(fmaxf(b[0] * scale, -448.f), 448.f);
    float b1 = fminf(fmaxf(b[1] * scale, -448.f), 448.f);
    float b2 = fminf(fmaxf(b[2] * scale, -448.f), 448.f);
    float b3 = fminf(fmaxf(b[3] * scale, -448.f), 448.f);
    uint2 r;
    r.x = cvt4_fp8(a0, a1, a2, a3);
    r.y = cvt4_fp8(b0, b1, b2, b3);
    q[i] = r;
  }
}

// ---------------- transpose + quantize: src [R][C] f32 -> dst [C][R] fp8 ----------------
__global__ __launch_bounds__(256) void quantT_kernel(const float* __restrict__ src,
                                                     u8* __restrict__ dst,
                                                     const unsigned* __restrict__ amax_bits,
                                                     int R, int C) {
  __shared__ float t[64][65];
  float amax = __uint_as_float(*amax_bits);
  float scale = 448.0f / fmaxf(amax, 1e-12f);
  int nbr = R >> 6;
  int br = (int)blockIdx.x % nbr, bc = (int)blockIdx.x / nbr;
  int r0 = br * 64, c0 = bc * 64;
  int tid = threadIdx.x;
  int lc = tid & 63, lr = tid >> 6;
#pragma unroll
  for (int i = 0; i < 16; ++i)
    t[lr + i * 4][lc] = src[(size_t)(r0 + lr + i * 4) * C + c0 + lc];
  __syncthreads();
  int qd = tid & 15, xbase = tid >> 4;
#pragma unroll
  for (int i = 0; i < 4; ++i) {
    int x = xbase + 16 * i;  // output row index (column of src tile)
    float v0 = fminf(fmaxf(t[4 * qd + 0][x] * scale, -448.f), 448.f);
    float v1 = fminf(fmaxf(t[4 * qd + 1][x] * scale, -448.f), 448.f);
    float v2 = fminf(fmaxf(t[4 * qd + 2][x] * scale, -448.f), 448.f);
    float v3 = fminf(fmaxf(t[4 * qd + 3][x] * scale, -448.f), 448.f);
    *(unsigned*)(dst + (size_t)(c0 + x) * R + r0 + 4 * qd) = cvt4_fp8(v0, v1, v2, v3);
  }
}

// ---------------- LDS address swizzle ----------------
// 16B-block XOR within 64B row, key = (row>>2)&3 (period 16 rows; verified
// conflict-free rounds 3/5/6: SQ_LDS_BANK_CONFLICT == 0).
__device__ __forceinline__ int swz_key(int r) { return (r >> 2) & 3; }

__device__ __forceinline__ int swz_off32(int r, int h) {
  return r * 64 + ((((h << 1) ^ swz_key(r)) << 4));
}

// Load a 32B MX-fp8 fragment (k-half h of row r) from a swizzled [*][64] tile.
__device__ __forceinline__ i32x8 ld_frag(const u8* base, int r, int h) {
  int o = swz_off32(r, h);
  i32x8 f;
  f.lo = *(const i32x4*)(base + o);
  f.hi = *(const i32x4*)(base + (o ^ 16));
  return f;
}

#define MFMA_MX(a, b, c) \
  __builtin_amdgcn_mfma_scale_f32_32x32x64_f8f6f4((a), (b), (c), 0, 0, 0, 0x7F7F7F7F, 0, 0x7F7F7F7F)

// ---------------- GEMM1: gate/up fused, NT, MX-fp8 ----------------
// 128x128 block tile, 512 threads = 8 waves (2M x 4N), per-wave 64x32 DUAL acc.
// Occupancy experiment: acc shrunk 128->64 VGPR so total ~115 fits the
// launch_bounds(512,4) 128-reg cap -> 16 waves/CU (4/SIMD) vs 8 before.
// Round-3 proven skeleton: single-buf LDS, 2x __syncthreads, dual-block cover.
__global__ __launch_bounds__(512, 4) void gemm1_gateup(
    const u8* __restrict__ Aq, const u8* __restrict__ Wq, const u8* __restrict__ Vq,
    const unsigned* __restrict__ scal, float* __restrict__ inter,
    unsigned* __restrict__ amax_mid, int M, int N, int K) {
  __shared__ __align__(16) u8 lA[8192], lW[8192], lV[8192];
  __shared__ float red[8];
  int tid = threadIdx.x;
  int lane = tid & 63, wid = tid >> 6;
  int wm = wid >> 2, wn = wid & 3;  // 2M x 4N waves, per-wave 64x32

  int nbn = N >> 7;
  int nwg = (int)gridDim.x;
  int bid = (int)blockIdx.x;
  int cpx = nwg >> 3;
  int swz = (bid & 7) * cpx + (bid >> 3);  // nwg % 8 == 0
  int bm = swz / nbn, bn = swz - bm * nbn;

  int r0 = tid >> 2;                           // 0..127
  int kblk = ((tid & 3) ^ swz_key(r0)) << 4;   // pre-swizzled global source chunk
  const u8* aS = Aq + (size_t)(bm * 128 + r0) * K + kblk;
  const u8* wS = Wq + (size_t)(bn * 128 + r0) * K + kblk;
  const u8* vS = Vq + (size_t)(bn * 128 + r0) * K + kblk;

  f32x16 g0 = (f32x16)(0.f), g1 = (f32x16)(0.f);
  f32x16 u0 = (f32x16)(0.f), u1 = (f32x16)(0.f);

  int rfrag = lane & 31;
  int h = lane >> 5;
  int arow = wm * 64 + rfrag;    // A rows 0..127
  int wrow = wn * 32 + rfrag;    // W/V rows 0..127

  for (int kt = 0; kt < K; kt += 64) {
    __syncthreads();
    gload_lds16(aS + kt, lA + tid * 16);
    gload_lds16(wS + kt, lW + tid * 16);
    gload_lds16(vS + kt, lV + tid * 16);
    __syncthreads();  // drains vmcnt -> staged data visible
    i32x8 a0 = ld_frag(lA, arow, h);
    i32x8 a1 = ld_frag(lA, arow + 32, h);
    i32x8 w0 = ld_frag(lW, wrow, h);
    i32x8 v0 = ld_frag(lV, wrow, h);
    g0 = MFMA_MX(a0, w0, g0);
    g1 = MFMA_MX(a1, w0, g1);
    u0 = MFMA_MX(a0, v0, u0);
    u1 = MFMA_MX(a1, v0, u1);
  }

  float ax = __uint_as_float(scal[0]);
  float aw = __uint_as_float(scal[1]);
  float av = __uint_as_float(scal[2]);
  float inv_x = 1.0f / (448.0f / fmaxf(ax, 1e-12f));
  float inv_w = 1.0f / (448.0f / fmaxf(aw, 1e-12f));
  float inv_v = 1.0f / (448.0f / fmaxf(av, 1e-12f));
  float sg = inv_x * inv_w, su = inv_x * inv_v;

  // C/D layout 32x32: col = lane&31, row = (reg&3) + 8*(reg>>2) + 4*(lane>>5)
  int rb = bm * 128 + wm * 64 + h * 4;
  int cb = bn * 128 + wn * 32 + rfrag;
  float lmax = 0.0f;
#pragma unroll
  for (int mi = 0; mi < 2; ++mi) {
    const f32x16& gg = mi ? g1 : g0;
    const f32x16& uu = mi ? u1 : u0;
#pragma unroll
    for (int q = 0; q < 16; ++q) {
      int rr = rb + mi * 32 + (q & 3) + 8 * (q >> 2);
      float gv = gg[q] * sg;
      float uv = uu[q] * su;
      float iv = gv / (1.0f + expf(-gv)) * uv;  // silu(g)*u
      inter[(size_t)rr * N + cb] = iv;
      lmax = fmaxf(lmax, fabsf(iv));
    }
  }
#pragma unroll
  for (int off = 32; off > 0; off >>= 1) lmax = fmaxf(lmax, __shfl_down(lmax, off));
  if (lane == 0) red[wid] = lmax;
  __syncthreads();
  if (tid == 0) {
    float v = red[0];
#pragma unroll
    for (int i = 1; i < 8; ++i) v = fmaxf(v, red[i]);
    atomicMax(amax_mid, __float_as_uint(v));
  }
}

// ---------------- GEMM2: down proj, NT vs pre-transposed w2 ----------------
// 128x256 block tile, 512 threads = 8 waves (2M x 4N), per-wave 64x64 single acc.
__global__ __launch_bounds__(512, 4) void gemm2_down(
    const u8* __restrict__ Aq, const u8* __restrict__ Bq,
    const unsigned* __restrict__ amax_a, const unsigned* __restrict__ amax_b,
    float* __restrict__ out, int M, int N, int K) {
  __shared__ __align__(16) u8 lA[8192], lB[16384];
  int tid = threadIdx.x;
  int lane = tid & 63, wid = tid >> 6;
  int wm = wid >> 2, wn = wid & 3;  // 2M x 4N waves, per-wave 64x64

  int nbn = N >> 8;                 // N/256
  int nwg = (int)gridDim.x;
  int bid = (int)blockIdx.x;
  int cpx = nwg >> 3;
  int swz = (bid & 7) * cpx + (bid >> 3);
  int bm = swz / nbn, bn = swz - bm * nbn;

  int r0 = tid >> 2;
  int kblk = ((tid & 3) ^ swz_key(r0)) << 4;
  const u8* aS = Aq + (size_t)(bm * 128 + r0) * K + kblk;
  const u8* bS = Bq + (size_t)(bn * 256 + r0) * K + kblk;
  size_t rK = (size_t)128 * K;   // B rows 128..255 (swz_key period 16 -> same kblk)

  f32x16 c00 = (f32x16)(0.f), c01 = (f32x16)(0.f);
  f32x16 c10 = (f32x16)(0.f), c11 = (f32x16)(0.f);

  int rfrag = lane & 31;
  int h = lane >> 5;
  int arow = wm * 64 + rfrag;    // 0..127
  int brow = wn * 64 + rfrag;    // 0..255

  for (int kt = 0; kt < K; kt += 64) {
    __syncthreads();
    gload_lds16(aS + kt, lA + tid * 16);
    gload_lds16(bS + kt, lB + tid * 16);
    gload_lds16(bS + kt + rK, lB + 8192 + tid * 16);
    __syncthreads();
    i32x8 a0 = ld_frag(lA, arow, h);
    i32x8 a1 = ld_frag(lA, arow + 32, h);
    i32x8 b0 = ld_frag(lB, brow, h);
    i32x8 b1 = ld_frag(lB, brow + 32, h);
    c00 = MFMA_MX(a0, b0, c00);
    c01 = MFMA_MX(a0, b1, c01);
    c10 = MFMA_MX(a1, b0, c10);
    c11 = MFMA_MX(a1, b1, c11);
  }

  float sa = 1.0f / (448.0f / fmaxf(__uint_as_float(*amax_a), 1e-12f));
  float sb = 1.0f / (448.0f / fmaxf(__uint_as_float(*amax_b), 1e-12f));
  float sc = sa * sb;

  int rb = bm * 128 + wm * 64 + h * 4;
  int cb = bn * 256 + wn * 64 + rfrag;
#pragma unroll
  for (int mi = 0; mi < 2; ++mi)
#pragma unroll
    for (int ni = 0; ni < 2; ++ni) {
      const f32x16& cc = mi ? (ni ? c11 : c10) : (ni ? c01 : c00);
#pragma unroll
      for (int q = 0; q < 16; ++q) {
        int rr = rb + mi * 32 + (q & 3) + 8 * (q >> 2);
        out[(size_t)rr * N + (cb + ni * 32)] = cc[q] * sc;
      }
    }
}

// ---------------- host launcher ----------------
extern "C" void kernel_launch(void* const* d_in, const int* in_sizes, int n_in,
                              void* d_out, int out_size, void* d_ws, size_t ws_size,
                              hipStream_t stream) {
  const float* x  = (const float*)d_in[0];
  const float* w1 = (const float*)d_in[1];
  const float* v1 = (const float*)d_in[2];
  const float* w2 = (const float*)d_in[3];
  const int M = 4096, H = 4096, F = 10752;

  u8* ws = (u8*)d_ws;
  unsigned* scal = (unsigned*)ws;          // [0]=x [1]=w1 [2]=v1 [3]=w2 [4]=mid
  u8* xq   = ws + 256;
  u8* w1q  = xq   + (size_t)M * H;
  u8* v1q  = w1q  + (size_t)F * H;
  u8* w2qT = v1q  + (size_t)F * H;
  u8* midq = w2qT + (size_t)F * H;
  float* inter = (float*)(midq + (size_t)M * F);

  hipMemsetAsync(scal, 0, 256, stream);
  amax_kernel<<<2048, 256, 0, stream>>>(x,  (size_t)M * H / 4, scal + 0);
  amax_kernel<<<2048, 256, 0, stream>>>(w1, (size_t)F * H / 4, scal + 1);
  amax_kernel<<<2048, 256, 0, stream>>>(v1, (size_t)F * H / 4, scal + 2);
  amax_kernel<<<2048, 256, 0, stream>>>(w2, (size_t)F * H / 4, scal + 3);

  quant_kernel<<<2048, 256, 0, stream>>>(x,  xq,  scal + 0, (size_t)M * H / 8);
  quant_kernel<<<2048, 256, 0, stream>>>(w1, w1q, scal + 1, (size_t)F * H / 8);
  quant_kernel<<<2048, 256, 0, stream>>>(v1, v1q, scal + 2, (size_t)F * H / 8);
  quantT_kernel<<<(F / 64) * (H / 64), 256, 0, stream>>>(w2, w2qT, scal + 3, F, H);

  gemm1_gateup<<<(M / 128) * (F / 128), 512, 0, stream>>>(xq, w1q, v1q, scal, inter,
                                                          scal + 4, M, F, H);
  quant_kernel<<<2048, 256, 0, stream>>>(inter, midq, scal + 4, (size_t)M * F / 8);
  gemm2_down<<<(M / 128) * (H / 256), 512, 0, stream>>>(midq, w2qT, scal + 4, scal + 3,
                                                        (float*)d_out, M, H, F);
}